// Round 8
// baseline (786.441 us; speedup 1.0000x reference)
//
#include <hip/hip_runtime.h>
#include <stdint.h>

#define N_ROWS 32768
#define D_DIM  512
#define K_CODES 4096

// ---- workspace layout (bytes) ----
#define WS_KEYS   0          // u64[32768]            -> 262144   (fallback only)
#define WS_XNORM  262144     // f32[32768]            -> 393216
#define WS_ENORM  393216     // f32[4096]             -> 409600
#define WS_PART   409600     // f32[16384]            -> 475136
#define WS_EMBT   475136     // f32[4096*512] = 8 MiB -> 8863744
// fast-path extras (hi-split only)
#define WS_EHIT   8863744    // u16[4096*512]  = 4 MiB  -> 13058048
#define WS_XHI    13058048   // u16[32768*512] = 32 MiB -> 46612480
#define WS_CNT    46612480   // u32[32768]              -> 46743552
#define WS_CAND   46743552   // u64[32768*64]  = 16 MiB -> 63520768
#define WS_NEED_FAST 63520768ull

// 1-product approx: sim ~ x0*e0 (bf16-truncated hi parts). err_max ~1.2e-2
// (dropped cross terms + fp32 accum-order delta). EPS >= 2*err -> 0.08.
// Verified: absmax == 0.0 at this EPS (rounds 5,6,7).
#define EPS_CAND 0.08f

typedef __attribute__((address_space(3))) unsigned int lds_uint;
typedef __attribute__((address_space(1))) const unsigned int glob_uint;
__device__ __forceinline__ void async_cp16(const void* g, void* l) {
    // 16B per lane, LDS dest = wave-uniform base + lane*16
    __builtin_amdgcn_global_load_lds((glob_uint*)g, (lds_uint*)l, 16, 0, 0);
}

typedef __attribute__((ext_vector_type(8))) short short8;
typedef __attribute__((ext_vector_type(4))) float f32x4;

__global__ __launch_bounds__(256) void k_init(unsigned long long* keys, unsigned int* cnt) {
    int t = blockIdx.x * 256 + threadIdx.x;
    if (t < N_ROWS) {
        keys[t] = ~0ull;
        if (cnt) cnt[t] = 0u;
    }
}

// ---------------------------------------------------------------------------
// k_prep_x (8192 blocks): each block owns rows 4B..4B+3 (2048 floats).
//  - split to bf16-hi (all 256 threads, vectorized)  [verbatim round-6 body]
//  - cnt init (blocks 0..127)
//  - xnorm of the SAME 4 rows by wave 0 with the VERBATIM old-wave lane
//    pattern (old kernel: wave w -> rows 4w..4w+3; here wave 0 plays wave
//    index B) -> bitwise-identical xnorm, x rows are L1/L2-hot (just read).
// Removes the separate 2048-block xnorm launch + its 64 MB HBM re-read.
// ---------------------------------------------------------------------------
__global__ __launch_bounds__(256) void k_prep_x(const float* __restrict__ x,
                                                unsigned short* __restrict__ xhi,
                                                unsigned int* __restrict__ cnt,
                                                float* __restrict__ xnorm) {
#pragma clang fp contract(off)
    const int bid = blockIdx.x;
    const int tid = threadIdx.x;
    if (bid < 128) cnt[bid * 256 + tid] = 0u;
    size_t t = (size_t)bid * 256 + tid;  // 8 floats per thread
    const float4 v0 = *(const float4*)(x + t * 8);
    const float4 v1 = *(const float4*)(x + t * 8 + 4);
    float vs[8] = {v0.x, v0.y, v0.z, v0.w, v1.x, v1.y, v1.z, v1.w};
    unsigned h[8];
#pragma unroll
    for (int i = 0; i < 8; ++i) h[i] = __float_as_uint(vs[i]) >> 16;
    uint4 ph = {h[0] | (h[1] << 16), h[2] | (h[3] << 16),
                h[4] | (h[5] << 16), h[6] | (h[7] << 16)};
    *(uint4*)(xhi + t * 8) = ph;

    // xnorm for rows 4*bid .. 4*bid+3 (wave 0 only; verbatim lane pattern)
    if (tid < 64) {
        int lane = tid;
        int l = lane & 15;
        int rowInWave = lane >> 4;
        int row = bid * 4 + rowInWave;
        const float* xr = x + (size_t)row * D_DIM;
        float B[4];
#pragma unroll
        for (int b = 0; b < 4; ++b) {
            const float* a = xr + b * 128;
            float r[8];
#pragma unroll
            for (int j = 0; j < 8; ++j) {
                float v = a[j * 16 + l];
                r[j] = v * v;
            }
            float V = ((r[0] + r[1]) + (r[2] + r[3])) + ((r[4] + r[5]) + (r[6] + r[7]));
            float T1 = V + __shfl_xor(V, 8);
            float T2 = T1 + __shfl_xor(T1, 4);
            float U  = T2 + __shfl_xor(T2, 2);
            B[b] = U + __shfl_xor(U, 1);
        }
        float total = (B[0] + B[1]) + (B[2] + B[3]);
        if (l == 0) xnorm[row] = total;
    }
}

// ---------------------------------------------------------------------------
// k_prep_e: fused {emb -> embT f32 + ehiT bf16-hi transpose} (blocks 0..511)
// and {enorm, strictly d-ascending serial per col} (blocks 512..575).
// ---------------------------------------------------------------------------
__global__ __launch_bounds__(256) void k_prep_e(const float* __restrict__ emb,
                                                float* __restrict__ embT,
                                                unsigned short* __restrict__ ehiT,
                                                float* __restrict__ enorm) {
#pragma clang fp contract(off)
    __shared__ float tile[64][65];
    const int bid = blockIdx.x;
    const int tid = threadIdx.x;
    if (bid < 512) {
        int k0 = (bid & 63) * 64;
        int d0 = (bid >> 6) * 64;
        int kk = tid & 63;
        int dth = tid >> 6;
#pragma unroll
        for (int r = 0; r < 16; ++r) {
            int d = dth + r * 4;
            tile[d][kk] = emb[(size_t)(d0 + d) * K_CODES + k0 + kk];
        }
        __syncthreads();
        int dOff = tid & 63;
        int kBase = tid >> 6;
#pragma unroll
        for (int r = 0; r < 16; ++r) {
            int k = kBase + r * 4;
            float v = tile[dOff][k];
            size_t o = (size_t)(k0 + k) * D_DIM + d0 + dOff;
            embT[o] = v;
            ehiT[o] = (unsigned short)(__float_as_uint(v) >> 16);
        }
    } else {
        if (tid < 64) {
            int k = (bid - 512) * 64 + tid;
            float v = emb[k];
            float acc = v * v;
#pragma unroll 8
            for (int d = 1; d < D_DIM; ++d) {
                float u = emb[(size_t)d * K_CODES + k];
                acc = acc + u * u;
            }
            enorm[k] = acc;
        }
    }
}

// fallback-path helpers (unchanged, known-good) -------------------------------
__global__ __launch_bounds__(256) void k_transpose(const float* __restrict__ emb,
                                                   float* __restrict__ embT) {
    __shared__ float tile[64][65];
    int k0 = blockIdx.x * 64;
    int d0 = blockIdx.y * 64;
    int tid = threadIdx.x;
    int kk = tid & 63;
    int dd = tid >> 6;
#pragma unroll
    for (int r = 0; r < 16; ++r) {
        int d = dd + r * 4;
        tile[d][kk] = emb[(size_t)(d0 + d) * K_CODES + k0 + kk];
    }
    __syncthreads();
    int dOff = tid & 63;
    int kBase = tid >> 6;
#pragma unroll
    for (int r = 0; r < 16; ++r) {
        int k = kBase + r * 4;
        embT[(size_t)(k0 + k) * D_DIM + d0 + dOff] = tile[dOff][k];
    }
}

__global__ __launch_bounds__(256) void k_xnorm(const float* __restrict__ x,
                                               float* __restrict__ xnorm) {
#pragma clang fp contract(off)
    int lane = threadIdx.x & 63;
    int l = lane & 15;
    int rowInWave = lane >> 4;
    int wave = blockIdx.x * 4 + (threadIdx.x >> 6);
    int row = wave * 4 + rowInWave;
    const float* xr = x + (size_t)row * D_DIM;
    float B[4];
#pragma unroll
    for (int b = 0; b < 4; ++b) {
        const float* a = xr + b * 128;
        float r[8];
#pragma unroll
        for (int j = 0; j < 8; ++j) {
            float v = a[j * 16 + l];
            r[j] = v * v;
        }
        float V = ((r[0] + r[1]) + (r[2] + r[3])) + ((r[4] + r[5]) + (r[6] + r[7]));
        float T1 = V + __shfl_xor(V, 8);
        float T2 = T1 + __shfl_xor(T1, 4);
        float U  = T2 + __shfl_xor(T2, 2);
        B[b] = U + __shfl_xor(U, 1);
    }
    float total = (B[0] + B[1]) + (B[2] + B[3]);
    if (l == 0) xnorm[row] = total;
}

__global__ __launch_bounds__(256) void k_enorm(const float* __restrict__ emb,
                                               float* __restrict__ enorm) {
#pragma clang fp contract(off)
    int k = blockIdx.x * 256 + threadIdx.x;
    float v = emb[k];
    float acc = v * v;
    for (int d = 1; d < D_DIM; ++d) {
        float u = emb[(size_t)d * K_CODES + k];
        acc = acc + u * u;
    }
    enorm[k] = acc;
}

// ---------------------------------------------------------------------------
// Fast path: 1-product bf16-hi MFMA approximate distances + eps-candidates.
// ROUND-6 STRUCTURE RESTORED (A+B both LDS-staged via global_load_lds,
// BK=32 double-buffered, counted-vmcnt: vmcnt(4) keeps next chunk's 4 cp16
// in flight across the barrier). Round-8 delta: __launch_bounds__(256,5)
// -> 5 blocks/CU (LDS 5*32KB = 160KB exactly; VGPR 64 <= 102 cap) for more
// independent-block diversity against the barrier/vmcnt stall. setprio
// removed (measured null, round 6).
// ---------------------------------------------------------------------------
__global__ __launch_bounds__(256, 5) void k_approx(
    const unsigned short* __restrict__ xhi, const unsigned short* __restrict__ ehiT,
    const float* __restrict__ xnorm, const float* __restrict__ enorm,
    unsigned int* __restrict__ cnt, unsigned long long* __restrict__ cand) {
    __shared__ short As[2][128 * 32];  // [buf][row m][k granule-swizzled]
    __shared__ short Bs[2][128 * 32];  // [buf][col n][k]
    const int tid = threadIdx.x;
    const int lane = tid & 63;
    const int wv = tid >> 6;
    const int rowBase = blockIdx.y * 128;
    const int colBase = blockIdx.x * 128;
    const int mBase = (wv >> 1) * 64;
    const int nBase = (wv & 1) * 64;

    f32x4 acc[4][4];
#pragma unroll
    for (int i = 0; i < 4; ++i)
#pragma unroll
        for (int j = 0; j < 4; ++j) acc[i][j] = (f32x4){0.f, 0.f, 0.f, 0.f};

    // staging: wave wv covers rows [wv*32, wv*32+32) of A and B.
    // lane -> (row = rr + lane>>2, slot = lane&3); slot holds global granule
    // g = slot ^ ((row>>1)&3)  (XOR involution; read side applies the same).
    auto STAGE = [&](int buf, int c) {
#pragma unroll
        for (int i = 0; i < 2; ++i) {
            const int rr = wv * 32 + i * 16;       // 16 rows per cp16
            const int row = rr + (lane >> 2);
            const int g = (lane & 3) ^ ((row >> 1) & 3);
            const size_t kO = (size_t)c * 32 + g * 8;
            async_cp16(xhi + (size_t)(rowBase + row) * 512 + kO, &As[buf][rr * 32]);
            async_cp16(ehiT + (size_t)(colBase + row) * 512 + kO, &Bs[buf][rr * 32]);
        }
    };

    const int gk = lane >> 4;   // k-slice 0..3 (8 shorts each)
    const int lm = lane & 15;

    auto COMPUTE = [&](int buf) {
        short8 a[4], b[4];
#pragma unroll
        for (int mf = 0; mf < 4; ++mf) {
            const int m = mBase + mf * 16 + lm;
            a[mf] = *(const short8*)&As[buf][m * 32 + ((gk ^ ((m >> 1) & 3)) << 3)];
        }
#pragma unroll
        for (int nf = 0; nf < 4; ++nf) {
            const int n = nBase + nf * 16 + lm;
            b[nf] = *(const short8*)&Bs[buf][n * 32 + ((gk ^ ((n >> 1) & 3)) << 3)];
        }
#pragma unroll
        for (int mf = 0; mf < 4; ++mf)
#pragma unroll
            for (int nf = 0; nf < 4; ++nf)
                acc[mf][nf] = __builtin_amdgcn_mfma_f32_16x16x32_bf16(a[mf], b[nf], acc[mf][nf], 0, 0, 0);
    };

    STAGE(0, 0);
    STAGE(1, 1);
#pragma unroll 1
    for (int c = 0; c < 15; ++c) {
        // STAGE(c)'s 4 loads done; STAGE(c+1)'s 4 stay in flight across barrier
        asm volatile("s_waitcnt vmcnt(4)" ::: "memory");
        __builtin_amdgcn_sched_barrier(0);
        __builtin_amdgcn_s_barrier();
        COMPUTE(c & 1);
        __builtin_amdgcn_sched_barrier(0);
        __builtin_amdgcn_s_barrier();   // all waves done reading buf[c&1]
        if (c < 14) STAGE(c & 1, c + 2);
    }
    // last chunk (c=15): only STAGE(15)'s 4 loads outstanding
    asm volatile("s_waitcnt vmcnt(0)" ::: "memory");
    __builtin_amdgcn_sched_barrier(0);
    __builtin_amdgcn_s_barrier();
    COMPUTE(1);

    // ---- epilogue: dd = (xn+en) - 2*sim; per-row block min; candidate append ----
    const int lr4 = (lane >> 4) * 4;  // C/D: row = (lane>>4)*4 + reg
    const int lc = lane & 15;         //      col = lane & 15
    float en[4], xn[4][4];
#pragma unroll
    for (int nf = 0; nf < 4; ++nf) en[nf] = enorm[colBase + nBase + nf * 16 + lc];
#pragma unroll
    for (int mf = 0; mf < 4; ++mf)
#pragma unroll
        for (int reg = 0; reg < 4; ++reg)
            xn[mf][reg] = xnorm[rowBase + mBase + mf * 16 + lr4 + reg];

#pragma unroll
    for (int mf = 0; mf < 4; ++mf)
#pragma unroll
        for (int nf = 0; nf < 4; ++nf) {
            f32x4 a = acc[mf][nf];
#pragma unroll
            for (int reg = 0; reg < 4; ++reg)
                a[reg] = (xn[mf][reg] + en[nf]) - 2.0f * a[reg];
            acc[mf][nf] = a;
        }

    __syncthreads();                 // done reading As/Bs; reuse As for row mins
    float* rm = (float*)&As[0][0];   // [2 col-halves][128 rows]
#pragma unroll
    for (int mf = 0; mf < 4; ++mf)
#pragma unroll
        for (int reg = 0; reg < 4; ++reg) {
            float v = fminf(fminf(acc[mf][0][reg], acc[mf][1][reg]),
                            fminf(acc[mf][2][reg], acc[mf][3][reg]));
            v = fminf(v, __shfl_xor(v, 1, 16));
            v = fminf(v, __shfl_xor(v, 2, 16));
            v = fminf(v, __shfl_xor(v, 4, 16));
            v = fminf(v, __shfl_xor(v, 8, 16));
            if (lc == 0) rm[(wv & 1) * 128 + mBase + mf * 16 + lr4 + reg] = v;
        }
    __syncthreads();

#pragma unroll
    for (int mf = 0; mf < 4; ++mf)
#pragma unroll
        for (int reg = 0; reg < 4; ++reg) {
            const int rLoc = mBase + mf * 16 + lr4 + reg;
            const float thr = fminf(rm[rLoc], rm[128 + rLoc]) + EPS_CAND;
            const int rowG = rowBase + rLoc;
#pragma unroll
            for (int nf = 0; nf < 4; ++nf) {
                float dd = acc[mf][nf][reg];
                if (dd <= thr) {
                    unsigned u = __float_as_uint(dd);
                    u = (u & 0x80000000u) ? ~u : (u | 0x80000000u);
                    const unsigned colG = (unsigned)(colBase + nBase + nf * 16 + lc);
                    unsigned long long key = ((unsigned long long)u << 32) | colG;
                    unsigned idx = atomicAdd(&cnt[rowG], 1u);
                    if (idx < 64u) cand[(size_t)rowG * 64 + idx] = key;
                }
            }
        }
}

// ---------------------------------------------------------------------------
// k_egather: fused exact-rescan + gather + loss (verbatim from round 6).
// ---------------------------------------------------------------------------
__global__ __launch_bounds__(256) void k_egather(
    const float* __restrict__ x, const float* __restrict__ embT,
    const float* __restrict__ xnorm, const float* __restrict__ enorm,
    const unsigned int* __restrict__ cnt, const unsigned long long* __restrict__ cand,
    float* __restrict__ out, float* __restrict__ partial) {
#pragma clang fp contract(off)
    __shared__ int idxsh[2];
    const int tid = threadIdx.x;
    const int w = tid >> 6;
    const int lane = tid & 63;
    if (w < 2) {
        const int row = blockIdx.x * 2 + w;
        const unsigned n = cnt[row];
        const float xn = xnorm[row];
        const float* xr = x + (size_t)row * D_DIM;
        unsigned long long ek = ~0ull;
        if (n <= 64u) {
            unsigned long long kk = ~0ull;
            if (lane < (int)n) kk = cand[(size_t)row * 64 + lane];
            unsigned long long mn = kk;
#pragma unroll
            for (int off = 32; off > 0; off >>= 1) {
                unsigned long long o = __shfl_xor(mn, off, 64);
                mn = o < mn ? o : mn;
            }
            unsigned mu = (unsigned)(mn >> 32);
            float mnf = __uint_as_float((mu & 0x80000000u) ? (mu & 0x7FFFFFFFu) : ~mu);
            if (lane < (int)n) {
                unsigned u = (unsigned)(kk >> 32);
                float ddA = __uint_as_float((u & 0x80000000u) ? (u & 0x7FFFFFFFu) : ~u);
                int col = (int)(unsigned)(kk & 0xFFFFFFFFull);
                if (ddA <= mnf + EPS_CAND) {
                    const float* er = embT + (size_t)col * D_DIM;
                    float acc = 0.f;
#pragma unroll 8
                    for (int d = 0; d < D_DIM; ++d) acc = fmaf(xr[d], er[d], acc);
                    float t1 = xn + enorm[col];
                    float dd = t1 - 2.0f * acc;  // 2*acc exact; single rounding
                    unsigned uu = __float_as_uint(dd);
                    uu = (uu & 0x80000000u) ? ~uu : (uu | 0x80000000u);
                    ek = ((unsigned long long)uu << 32) | (unsigned)col;
                }
            }
        } else {
            // overflow (safety net): exact scan of all columns for this row
            for (int col = lane; col < K_CODES; col += 64) {
                const float* er = embT + (size_t)col * D_DIM;
                float acc = 0.f;
#pragma unroll 8
                for (int d = 0; d < D_DIM; ++d) acc = fmaf(xr[d], er[d], acc);
                float t1 = xn + enorm[col];
                float dd = t1 - 2.0f * acc;
                unsigned uu = __float_as_uint(dd);
                uu = (uu & 0x80000000u) ? ~uu : (uu | 0x80000000u);
                unsigned long long key = ((unsigned long long)uu << 32) | (unsigned)col;
                ek = key < ek ? key : ek;
            }
        }
#pragma unroll
        for (int off = 32; off > 0; off >>= 1) {
            unsigned long long o = __shfl_xor(ek, off, 64);
            ek = o < ek ? o : ek;
        }
        if (lane == 0) idxsh[w] = (int)(unsigned)(ek & 0xFFFFFFFFull);
    }
    __syncthreads();
    // ---- phase 2: verbatim verified k_gather (embIsT = 1) ----
    int row = blockIdx.x * 2 + (tid >> 7);
    int d = (tid & 127) * 4;
    int idx = idxsh[tid >> 7];
    float4 q = *(const float4*)&embT[(size_t)idx * D_DIM + d];
    float4 xv = *(const float4*)&x[(size_t)row * D_DIM + d];
    float d0 = q.x - xv.x, d1 = q.y - xv.y, d2 = q.z - xv.z, d3 = q.w - xv.w;
    float4 o;
    o.x = xv.x + d0; o.y = xv.y + d1; o.z = xv.z + d2; o.w = xv.w + d3;
    *(float4*)&out[(size_t)row * D_DIM + d] = o;
    float s = (d0 * d0 + d1 * d1) + (d2 * d2 + d3 * d3);
#pragma unroll
    for (int off = 32; off > 0; off >>= 1) s += __shfl_xor(s, off, 64);
    __shared__ float wsum[4];
    int wvv = tid >> 6;
    if (lane == 0) wsum[wvv] = s;
    __syncthreads();
    if (tid == 0) partial[blockIdx.x] = (wsum[0] + wsum[1]) + (wsum[2] + wsum[3]);
}

// ---------------------------------------------------------------------------
// Fallback exact fp32 GEMM+argmin (known-good), used when ws is too small.
// ---------------------------------------------------------------------------
__global__ __launch_bounds__(256, 3) void k_argmin(const float* __restrict__ x,
                                                   const float* __restrict__ emb,
                                                   const float* __restrict__ xnorm,
                                                   const float* __restrict__ enorm,
                                                   unsigned long long* __restrict__ keys) {
    __shared__ float As[16 * 128];
    __shared__ float Bs[2][16 * 128];
    const int tid = threadIdx.x;
    const int tx = tid & 15;
    const int ty = tid >> 4;
    const int rowBase = blockIdx.x * 128;
    const int colBase = blockIdx.y * 128;
    const int lane = tid & 63;
    const int wv = tid >> 6;

    float acc[8][8];
#pragma unroll
    for (int j = 0; j < 8; ++j)
#pragma unroll
        for (int i = 0; i < 8; ++i) acc[j][i] = 0.f;

    const int lr = tid >> 2;
    const int ld4 = (tid & 3) * 4;
    const float* gA0 = x + (size_t)(rowBase + lr) * D_DIM + ld4;
    const float* gA1 = gA0 + (size_t)64 * D_DIM;

    const int bd0 = 2 * wv;
    const float* gBbase = emb + (size_t)(bd0 + (lane >> 5)) * K_CODES + colBase + (lane & 31) * 4;

    async_cp16(gBbase, &Bs[0][bd0 * 128]);
    async_cp16(gBbase + (size_t)8 * K_CODES, &Bs[0][(8 + bd0) * 128]);
    float4 pa0 = *(const float4*)gA0;
    float4 pa1 = *(const float4*)gA1;

    const int sg = lr >> 2;
    const int sc = lr & 3;

    for (int c = 0; c < 32; ++c) {
        __syncthreads();
        {
            const float a0v[4] = {pa0.x, pa0.y, pa0.z, pa0.w};
            const float a1v[4] = {pa1.x, pa1.y, pa1.z, pa1.w};
#pragma unroll
            for (int i = 0; i < 4; ++i) {
                int d = ld4 + i;
                int idx = d * 128 + ((sg ^ d) << 2) + sc;
                As[idx] = a0v[i];
                As[idx + 64] = a1v[i];
            }
        }
        __syncthreads();
        if (c + 1 < 32) {
            const int dn = (c + 1) * 16;
            float* bdst = &Bs[(c + 1) & 1][0];
            async_cp16(gBbase + (size_t)dn * K_CODES, bdst + bd0 * 128);
            async_cp16(gBbase + (size_t)(dn + 8) * K_CODES, bdst + (8 + bd0) * 128);
            pa0 = *(const float4*)(gA0 + dn);
            pa1 = *(const float4*)(gA1 + dn);
        }
        const float* B = &Bs[c & 1][0];
#pragma unroll
        for (int d = 0; d < 16; ++d) {
            const float4 a0 = *(const float4*)&As[d * 128 + ((ty ^ d) << 2)];
            const float4 a1 = *(const float4*)&As[d * 128 + ((ty ^ d) << 2) + 64];
            const float4 b0 = *(const float4*)&B[d * 128 + (tx << 2)];
            const float4 b1 = *(const float4*)&B[d * 128 + (tx << 2) + 64];
            const float av[8] = {a0.x, a0.y, a0.z, a0.w, a1.x, a1.y, a1.z, a1.w};
            const float bv[8] = {b0.x, b0.y, b0.z, b0.w, b1.x, b1.y, b1.z, b1.w};
#pragma unroll
            for (int j = 0; j < 8; ++j)
#pragma unroll
                for (int i = 0; i < 8; ++i)
                    acc[j][i] = fmaf(av[j], bv[i], acc[j][i]);
        }
    }

    float en[8];
    *(float4*)&en[0] = *(const float4*)&enorm[colBase + 4 * tx];
    *(float4*)&en[4] = *(const float4*)&enorm[colBase + 64 + 4 * tx];
#pragma unroll
    for (int j = 0; j < 8; ++j) {
        int row = rowBase + ((j < 4) ? (4 * ty + j) : (64 + 4 * ty + (j - 4)));
        float A = xnorm[row];
        unsigned long long best = ~0ull;
#pragma unroll
        for (int i = 0; i < 8; ++i) {
            int col = colBase + ((i < 4) ? (4 * tx + i) : (64 + 4 * tx + (i - 4)));
            float t1 = A + en[i];
            float dd = t1 - 2.0f * acc[j][i];
            unsigned u = __float_as_uint(dd);
            u = (u & 0x80000000u) ? ~u : (u | 0x80000000u);
            unsigned long long key = ((unsigned long long)u << 32) | (unsigned)col;
            best = key < best ? key : best;
        }
#pragma unroll
        for (int off = 8; off > 0; off >>= 1) {
            unsigned long long other = __shfl_xor(best, off, 16);
            best = other < best ? other : best;
        }
        if (tx == 0) atomicMin(&keys[row], best);
    }
}

// fallback gather (reads keys), unchanged
__global__ __launch_bounds__(256) void k_gather(const float* __restrict__ x,
                                                const float* __restrict__ embSrc,
                                                int embIsT,
                                                const unsigned long long* __restrict__ keys,
                                                float* __restrict__ out,
                                                float* __restrict__ partial) {
#pragma clang fp contract(off)
    int tid = threadIdx.x;
    int row = blockIdx.x * 2 + (tid >> 7);
    int d = (tid & 127) * 4;
    int idx = (int)(keys[row] & 0xFFFFFFFFull);
    float4 q;
    if (embIsT) {
        q = *(const float4*)&embSrc[(size_t)idx * D_DIM + d];
    } else {
        q.x = embSrc[(size_t)(d + 0) * K_CODES + idx];
        q.y = embSrc[(size_t)(d + 1) * K_CODES + idx];
        q.z = embSrc[(size_t)(d + 2) * K_CODES + idx];
        q.w = embSrc[(size_t)(d + 3) * K_CODES + idx];
    }
    float4 xv = *(const float4*)&x[(size_t)row * D_DIM + d];
    float d0 = q.x - xv.x, d1 = q.y - xv.y, d2 = q.z - xv.z, d3 = q.w - xv.w;
    float4 o;
    o.x = xv.x + d0; o.y = xv.y + d1; o.z = xv.z + d2; o.w = xv.w + d3;
    *(float4*)&out[(size_t)row * D_DIM + d] = o;
    float s = (d0 * d0 + d1 * d1) + (d2 * d2 + d3 * d3);
#pragma unroll
    for (int off = 32; off > 0; off >>= 1) s += __shfl_xor(s, off, 64);
    __shared__ float wsum[4];
    int lane = tid & 63, wvv = tid >> 6;
    if (lane == 0) wsum[wvv] = s;
    __syncthreads();
    if (tid == 0) partial[blockIdx.x] = (wsum[0] + wsum[1]) + (wsum[2] + wsum[3]);
}

__global__ __launch_bounds__(256) void k_reduce(const float* __restrict__ partial,
                                                float* __restrict__ out) {
    float s = 0.f;
    for (int i = threadIdx.x; i < 16384; i += 256) s += partial[i];
#pragma unroll
    for (int off = 32; off > 0; off >>= 1) s += __shfl_xor(s, off, 64);
    __shared__ float wsum[4];
    int lane = threadIdx.x & 63, wv = threadIdx.x >> 6;
    if (lane == 0) wsum[wv] = s;
    __syncthreads();
    if (threadIdx.x == 0) {
        float t = (wsum[0] + wsum[1]) + (wsum[2] + wsum[3]);
        float m = t / 16777216.f;               // mean((q-x)^2), N*D = 2^24
        out[(size_t)N_ROWS * D_DIM] = 0.25f * m + m;  // beta*m + m
    }
}

extern "C" void kernel_launch(void* const* d_in, const int* in_sizes, int n_in,
                              void* d_out, int out_size, void* d_ws, size_t ws_size,
                              hipStream_t stream) {
    const float* x = (const float*)d_in[0];
    const float* emb = (const float*)d_in[1];
    float* out = (float*)d_out;
    char* ws = (char*)d_ws;

    unsigned long long* keys = (unsigned long long*)(ws + WS_KEYS);
    float* xnorm = (float*)(ws + WS_XNORM);
    float* enorm = (float*)(ws + WS_ENORM);
    float* partial = (float*)(ws + WS_PART);
    float* embT = (float*)(ws + WS_EMBT);

    if (ws_size >= WS_NEED_FAST) {
        unsigned short* ehiT = (unsigned short*)(ws + WS_EHIT);
        unsigned short* xhi = (unsigned short*)(ws + WS_XHI);
        unsigned int* cnt = (unsigned int*)(ws + WS_CNT);
        unsigned long long* cand = (unsigned long long*)(ws + WS_CAND);

        hipLaunchKernelGGL(k_prep_x, dim3(8192), dim3(256), 0, stream, x, xhi, cnt, xnorm);
        hipLaunchKernelGGL(k_prep_e, dim3(576), dim3(256), 0, stream, emb, embT, ehiT, enorm);
        // grid: x = col-blocks (32), y = row-blocks (256) -> A-panel temporal locality
        hipLaunchKernelGGL(k_approx, dim3(K_CODES / 128, N_ROWS / 128), dim3(256), 0, stream,
                           xhi, ehiT, xnorm, enorm, cnt, cand);
        hipLaunchKernelGGL(k_egather, dim3(N_ROWS / 2), dim3(256), 0, stream,
                           x, embT, xnorm, enorm, cnt, cand, out, partial);
        hipLaunchKernelGGL(k_reduce, dim3(1), dim3(256), 0, stream, partial, out);
    } else {
        size_t need = WS_EMBT + (size_t)K_CODES * D_DIM * sizeof(float);
        int useT = (ws_size >= need) ? 1 : 0;

        hipLaunchKernelGGL(k_init, dim3(128), dim3(256), 0, stream, keys, (unsigned int*)nullptr);
        if (useT)
            hipLaunchKernelGGL(k_transpose, dim3(K_CODES / 64, D_DIM / 64), dim3(256), 0, stream,
                               emb, embT);
        hipLaunchKernelGGL(k_xnorm, dim3(N_ROWS / 16), dim3(256), 0, stream, x, xnorm);
        hipLaunchKernelGGL(k_enorm, dim3(K_CODES / 256), dim3(256), 0, stream, emb, enorm);
        hipLaunchKernelGGL(k_argmin, dim3(N_ROWS / 128, K_CODES / 128), dim3(256), 0, stream,
                           x, emb, xnorm, enorm, keys);
        hipLaunchKernelGGL(k_gather, dim3(N_ROWS / 2), dim3(256), 0, stream,
                           x, useT ? embT : emb, useT, keys, out, partial);
        hipLaunchKernelGGL(k_reduce, dim3(1), dim3(256), 0, stream, partial, out);
    }
}

// Round 9
// 758.025 us; speedup vs baseline: 1.0375x; 1.0375x over previous
//
#include <hip/hip_runtime.h>
#include <stdint.h>

#define N_ROWS 32768
#define D_DIM  512
#define K_CODES 4096

// ---- workspace layout (bytes) ----
#define WS_KEYS   0          // u64[32768]            -> 262144   (fallback only)
#define WS_XNORM  262144     // f32[32768]            -> 393216
#define WS_ENORM  393216     // f32[4096]             -> 409600
#define WS_PART   409600     // f32[16384]            -> 475136
#define WS_EMBT   475136     // f32[4096*512] = 8 MiB -> 8863744
// fast-path extras (hi-split only)
#define WS_EHIT   8863744    // u16[4096*512]  = 4 MiB  -> 13058048
#define WS_XHI    13058048   // u16[32768*512] = 32 MiB -> 46612480
#define WS_CNT    46612480   // u32[32768]              -> 46743552
#define WS_CAND   46743552   // u64[32768*64]  = 16 MiB -> 63520768
#define WS_NEED_FAST 63520768ull

// 1-product approx: sim ~ x0*e0 (bf16-truncated hi parts). err_max ~1.2e-2
// (dropped cross terms + fp32 accum-order delta). EPS >= 2*err -> 0.08.
// Verified: absmax == 0.0 at this EPS (rounds 5,6,7,8).
#define EPS_CAND 0.08f

typedef __attribute__((address_space(3))) unsigned int lds_uint;
typedef __attribute__((address_space(1))) const unsigned int glob_uint;
__device__ __forceinline__ void async_cp16(const void* g, void* l) {
    // 16B per lane, LDS dest = wave-uniform base + lane*16
    __builtin_amdgcn_global_load_lds((glob_uint*)g, (lds_uint*)l, 16, 0, 0);
}

typedef __attribute__((ext_vector_type(8))) short short8;
typedef __attribute__((ext_vector_type(4))) float f32x4;

__global__ __launch_bounds__(256) void k_init(unsigned long long* keys, unsigned int* cnt) {
    int t = blockIdx.x * 256 + threadIdx.x;
    if (t < N_ROWS) {
        keys[t] = ~0ull;
        if (cnt) cnt[t] = 0u;
    }
}

// ---------------------------------------------------------------------------
// k_prep_x (8192 blocks): split to bf16-hi + cnt init + xnorm of the block's
// own 4 rows (wave 0, verbatim lane pattern -> bitwise-identical xnorm).
// ---------------------------------------------------------------------------
__global__ __launch_bounds__(256) void k_prep_x(const float* __restrict__ x,
                                                unsigned short* __restrict__ xhi,
                                                unsigned int* __restrict__ cnt,
                                                float* __restrict__ xnorm) {
#pragma clang fp contract(off)
    const int bid = blockIdx.x;
    const int tid = threadIdx.x;
    if (bid < 128) cnt[bid * 256 + tid] = 0u;
    size_t t = (size_t)bid * 256 + tid;  // 8 floats per thread
    const float4 v0 = *(const float4*)(x + t * 8);
    const float4 v1 = *(const float4*)(x + t * 8 + 4);
    float vs[8] = {v0.x, v0.y, v0.z, v0.w, v1.x, v1.y, v1.z, v1.w};
    unsigned h[8];
#pragma unroll
    for (int i = 0; i < 8; ++i) h[i] = __float_as_uint(vs[i]) >> 16;
    uint4 ph = {h[0] | (h[1] << 16), h[2] | (h[3] << 16),
                h[4] | (h[5] << 16), h[6] | (h[7] << 16)};
    *(uint4*)(xhi + t * 8) = ph;

    // xnorm for rows 4*bid .. 4*bid+3 (wave 0 only; verbatim lane pattern)
    if (tid < 64) {
        int lane = tid;
        int l = lane & 15;
        int rowInWave = lane >> 4;
        int row = bid * 4 + rowInWave;
        const float* xr = x + (size_t)row * D_DIM;
        float B[4];
#pragma unroll
        for (int b = 0; b < 4; ++b) {
            const float* a = xr + b * 128;
            float r[8];
#pragma unroll
            for (int j = 0; j < 8; ++j) {
                float v = a[j * 16 + l];
                r[j] = v * v;
            }
            float V = ((r[0] + r[1]) + (r[2] + r[3])) + ((r[4] + r[5]) + (r[6] + r[7]));
            float T1 = V + __shfl_xor(V, 8);
            float T2 = T1 + __shfl_xor(T1, 4);
            float U  = T2 + __shfl_xor(T2, 2);
            B[b] = U + __shfl_xor(U, 1);
        }
        float total = (B[0] + B[1]) + (B[2] + B[3]);
        if (l == 0) xnorm[row] = total;
    }
}

// ---------------------------------------------------------------------------
// k_prep_e: fused {emb -> embT f32 + ehiT bf16-hi transpose} (blocks 0..511)
// and {enorm, strictly d-ascending serial per col} (blocks 512..575).
// ---------------------------------------------------------------------------
__global__ __launch_bounds__(256) void k_prep_e(const float* __restrict__ emb,
                                                float* __restrict__ embT,
                                                unsigned short* __restrict__ ehiT,
                                                float* __restrict__ enorm) {
#pragma clang fp contract(off)
    __shared__ float tile[64][65];
    const int bid = blockIdx.x;
    const int tid = threadIdx.x;
    if (bid < 512) {
        int k0 = (bid & 63) * 64;
        int d0 = (bid >> 6) * 64;
        int kk = tid & 63;
        int dth = tid >> 6;
#pragma unroll
        for (int r = 0; r < 16; ++r) {
            int d = dth + r * 4;
            tile[d][kk] = emb[(size_t)(d0 + d) * K_CODES + k0 + kk];
        }
        __syncthreads();
        int dOff = tid & 63;
        int kBase = tid >> 6;
#pragma unroll
        for (int r = 0; r < 16; ++r) {
            int k = kBase + r * 4;
            float v = tile[dOff][k];
            size_t o = (size_t)(k0 + k) * D_DIM + d0 + dOff;
            embT[o] = v;
            ehiT[o] = (unsigned short)(__float_as_uint(v) >> 16);
        }
    } else {
        if (tid < 64) {
            int k = (bid - 512) * 64 + tid;
            float v = emb[k];
            float acc = v * v;
#pragma unroll 8
            for (int d = 1; d < D_DIM; ++d) {
                float u = emb[(size_t)d * K_CODES + k];
                acc = acc + u * u;
            }
            enorm[k] = acc;
        }
    }
}

// fallback-path helpers (unchanged, known-good) -------------------------------
__global__ __launch_bounds__(256) void k_transpose(const float* __restrict__ emb,
                                                   float* __restrict__ embT) {
    __shared__ float tile[64][65];
    int k0 = blockIdx.x * 64;
    int d0 = blockIdx.y * 64;
    int tid = threadIdx.x;
    int kk = tid & 63;
    int dd = tid >> 6;
#pragma unroll
    for (int r = 0; r < 16; ++r) {
        int d = dd + r * 4;
        tile[d][kk] = emb[(size_t)(d0 + d) * K_CODES + k0 + kk];
    }
    __syncthreads();
    int dOff = tid & 63;
    int kBase = tid >> 6;
#pragma unroll
    for (int r = 0; r < 16; ++r) {
        int k = kBase + r * 4;
        embT[(size_t)(k0 + k) * D_DIM + d0 + dOff] = tile[dOff][k];
    }
}

__global__ __launch_bounds__(256) void k_xnorm(const float* __restrict__ x,
                                               float* __restrict__ xnorm) {
#pragma clang fp contract(off)
    int lane = threadIdx.x & 63;
    int l = lane & 15;
    int rowInWave = lane >> 4;
    int wave = blockIdx.x * 4 + (threadIdx.x >> 6);
    int row = wave * 4 + rowInWave;
    const float* xr = x + (size_t)row * D_DIM;
    float B[4];
#pragma unroll
    for (int b = 0; b < 4; ++b) {
        const float* a = xr + b * 128;
        float r[8];
#pragma unroll
        for (int j = 0; j < 8; ++j) {
            float v = a[j * 16 + l];
            r[j] = v * v;
        }
        float V = ((r[0] + r[1]) + (r[2] + r[3])) + ((r[4] + r[5]) + (r[6] + r[7]));
        float T1 = V + __shfl_xor(V, 8);
        float T2 = T1 + __shfl_xor(T1, 4);
        float U  = T2 + __shfl_xor(T2, 2);
        B[b] = U + __shfl_xor(U, 1);
    }
    float total = (B[0] + B[1]) + (B[2] + B[3]);
    if (l == 0) xnorm[row] = total;
}

__global__ __launch_bounds__(256) void k_enorm(const float* __restrict__ emb,
                                               float* __restrict__ enorm) {
#pragma clang fp contract(off)
    int k = blockIdx.x * 256 + threadIdx.x;
    float v = emb[k];
    float acc = v * v;
    for (int d = 1; d < D_DIM; ++d) {
        float u = emb[(size_t)d * K_CODES + k];
        acc = acc + u * u;
    }
    enorm[k] = acc;
}

// ---------------------------------------------------------------------------
// Fast path: 1-product bf16-hi MFMA approximate distances + eps-candidates.
// Round-9: TRIPLE-buffered A+B (48 KB) -> ONE barrier per chunk.
//   chunk c: waitcnt vmcnt(4)  [S(c) done; S(c+1) in flight]
//            s_barrier         [all waves' S(c) landed; COMPUTE(c-1) done]
//            STAGE(c+2) -> buf[(c+2)%3] = buf[(c-1)%3]  (readers passed bar)
//            COMPUTE(c)        [buf[c%3]]
// vmcnt: 8 outstanding at chunk top; vmcnt(4) retires S(c) in-order;
// vmcnt(0) only at c=15. launch_bounds(256,3): VGPR cap ~170 -> NO spill
// (round-8 lesson: (256,5) capped VGPR at 48, spilled acc, WRITE 259 MB).
// COMPUTE body verbatim round-6 -> bit-identical candidates.
// ---------------------------------------------------------------------------
__global__ __launch_bounds__(256, 3) void k_approx(
    const unsigned short* __restrict__ xhi, const unsigned short* __restrict__ ehiT,
    const float* __restrict__ xnorm, const float* __restrict__ enorm,
    unsigned int* __restrict__ cnt, unsigned long long* __restrict__ cand) {
    __shared__ short As[3][128 * 32];  // [buf][row m][k granule-swizzled]
    __shared__ short Bs[3][128 * 32];  // [buf][col n][k]
    const int tid = threadIdx.x;
    const int lane = tid & 63;
    const int wv = tid >> 6;
    const int rowBase = blockIdx.y * 128;
    const int colBase = blockIdx.x * 128;
    const int mBase = (wv >> 1) * 64;
    const int nBase = (wv & 1) * 64;

    f32x4 acc[4][4];
#pragma unroll
    for (int i = 0; i < 4; ++i)
#pragma unroll
        for (int j = 0; j < 4; ++j) acc[i][j] = (f32x4){0.f, 0.f, 0.f, 0.f};

    // staging: wave wv covers rows [wv*32, wv*32+32) of A and B.
    // lane -> (row = rr + lane>>2, slot = lane&3); slot holds global granule
    // g = slot ^ ((row>>1)&3)  (XOR involution; read side applies the same).
    auto STAGE = [&](int buf, int c) {
#pragma unroll
        for (int i = 0; i < 2; ++i) {
            const int rr = wv * 32 + i * 16;       // 16 rows per cp16
            const int row = rr + (lane >> 2);
            const int g = (lane & 3) ^ ((row >> 1) & 3);
            const size_t kO = (size_t)c * 32 + g * 8;
            async_cp16(xhi + (size_t)(rowBase + row) * 512 + kO, &As[buf][rr * 32]);
            async_cp16(ehiT + (size_t)(colBase + row) * 512 + kO, &Bs[buf][rr * 32]);
        }
    };

    const int gk = lane >> 4;   // k-slice 0..3 (8 shorts each)
    const int lm = lane & 15;

    auto COMPUTE = [&](int buf) {
        short8 a[4], b[4];
#pragma unroll
        for (int mf = 0; mf < 4; ++mf) {
            const int m = mBase + mf * 16 + lm;
            a[mf] = *(const short8*)&As[buf][m * 32 + ((gk ^ ((m >> 1) & 3)) << 3)];
        }
#pragma unroll
        for (int nf = 0; nf < 4; ++nf) {
            const int n = nBase + nf * 16 + lm;
            b[nf] = *(const short8*)&Bs[buf][n * 32 + ((gk ^ ((n >> 1) & 3)) << 3)];
        }
#pragma unroll
        for (int mf = 0; mf < 4; ++mf)
#pragma unroll
            for (int nf = 0; nf < 4; ++nf)
                acc[mf][nf] = __builtin_amdgcn_mfma_f32_16x16x32_bf16(a[mf], b[nf], acc[mf][nf], 0, 0, 0);
    };

    STAGE(0, 0);
    STAGE(1, 1);
#pragma unroll 1
    for (int c = 0; c < 16; ++c) {
        // S(c) complete for this wave; S(c+1)'s 4 stay in flight
        if (c < 15) {
            asm volatile("s_waitcnt vmcnt(4)" ::: "memory");
        } else {
            asm volatile("s_waitcnt vmcnt(0)" ::: "memory");
        }
        __builtin_amdgcn_sched_barrier(0);
        __builtin_amdgcn_s_barrier();   // all S(c) landed; all COMPUTE(c-1) done
        if (c + 2 < 16) STAGE((c + 2) % 3, c + 2);  // overwrites buf[(c-1)%3]: safe
        COMPUTE(c % 3);
    }

    // ---- epilogue: dd = (xn+en) - 2*sim; per-row block min; candidate append ----
    const int lr4 = (lane >> 4) * 4;  // C/D: row = (lane>>4)*4 + reg
    const int lc = lane & 15;         //      col = lane & 15
    float en[4], xn[4][4];
#pragma unroll
    for (int nf = 0; nf < 4; ++nf) en[nf] = enorm[colBase + nBase + nf * 16 + lc];
#pragma unroll
    for (int mf = 0; mf < 4; ++mf)
#pragma unroll
        for (int reg = 0; reg < 4; ++reg)
            xn[mf][reg] = xnorm[rowBase + mBase + mf * 16 + lr4 + reg];

#pragma unroll
    for (int mf = 0; mf < 4; ++mf)
#pragma unroll
        for (int nf = 0; nf < 4; ++nf) {
            f32x4 a = acc[mf][nf];
#pragma unroll
            for (int reg = 0; reg < 4; ++reg)
                a[reg] = (xn[mf][reg] + en[nf]) - 2.0f * a[reg];
            acc[mf][nf] = a;
        }

    __syncthreads();                 // done reading As/Bs; reuse As for row mins
    float* rm = (float*)&As[0][0];   // [2 col-halves][128 rows]
#pragma unroll
    for (int mf = 0; mf < 4; ++mf)
#pragma unroll
        for (int reg = 0; reg < 4; ++reg) {
            float v = fminf(fminf(acc[mf][0][reg], acc[mf][1][reg]),
                            fminf(acc[mf][2][reg], acc[mf][3][reg]));
            v = fminf(v, __shfl_xor(v, 1, 16));
            v = fminf(v, __shfl_xor(v, 2, 16));
            v = fminf(v, __shfl_xor(v, 4, 16));
            v = fminf(v, __shfl_xor(v, 8, 16));
            if (lc == 0) rm[(wv & 1) * 128 + mBase + mf * 16 + lr4 + reg] = v;
        }
    __syncthreads();

#pragma unroll
    for (int mf = 0; mf < 4; ++mf)
#pragma unroll
        for (int reg = 0; reg < 4; ++reg) {
            const int rLoc = mBase + mf * 16 + lr4 + reg;
            const float thr = fminf(rm[rLoc], rm[128 + rLoc]) + EPS_CAND;
            const int rowG = rowBase + rLoc;
#pragma unroll
            for (int nf = 0; nf < 4; ++nf) {
                float dd = acc[mf][nf][reg];
                if (dd <= thr) {
                    unsigned u = __float_as_uint(dd);
                    u = (u & 0x80000000u) ? ~u : (u | 0x80000000u);
                    const unsigned colG = (unsigned)(colBase + nBase + nf * 16 + lc);
                    unsigned long long key = ((unsigned long long)u << 32) | colG;
                    unsigned idx = atomicAdd(&cnt[rowG], 1u);
                    if (idx < 64u) cand[(size_t)rowG * 64 + idx] = key;
                }
            }
        }
}

// ---------------------------------------------------------------------------
// k_egather: fused exact-rescan + gather + loss (verbatim from round 6).
// ---------------------------------------------------------------------------
__global__ __launch_bounds__(256) void k_egather(
    const float* __restrict__ x, const float* __restrict__ embT,
    const float* __restrict__ xnorm, const float* __restrict__ enorm,
    const unsigned int* __restrict__ cnt, const unsigned long long* __restrict__ cand,
    float* __restrict__ out, float* __restrict__ partial) {
#pragma clang fp contract(off)
    __shared__ int idxsh[2];
    const int tid = threadIdx.x;
    const int w = tid >> 6;
    const int lane = tid & 63;
    if (w < 2) {
        const int row = blockIdx.x * 2 + w;
        const unsigned n = cnt[row];
        const float xn = xnorm[row];
        const float* xr = x + (size_t)row * D_DIM;
        unsigned long long ek = ~0ull;
        if (n <= 64u) {
            unsigned long long kk = ~0ull;
            if (lane < (int)n) kk = cand[(size_t)row * 64 + lane];
            unsigned long long mn = kk;
#pragma unroll
            for (int off = 32; off > 0; off >>= 1) {
                unsigned long long o = __shfl_xor(mn, off, 64);
                mn = o < mn ? o : mn;
            }
            unsigned mu = (unsigned)(mn >> 32);
            float mnf = __uint_as_float((mu & 0x80000000u) ? (mu & 0x7FFFFFFFu) : ~mu);
            if (lane < (int)n) {
                unsigned u = (unsigned)(kk >> 32);
                float ddA = __uint_as_float((u & 0x80000000u) ? (u & 0x7FFFFFFFu) : ~u);
                int col = (int)(unsigned)(kk & 0xFFFFFFFFull);
                if (ddA <= mnf + EPS_CAND) {
                    const float* er = embT + (size_t)col * D_DIM;
                    float acc = 0.f;
#pragma unroll 8
                    for (int d = 0; d < D_DIM; ++d) acc = fmaf(xr[d], er[d], acc);
                    float t1 = xn + enorm[col];
                    float dd = t1 - 2.0f * acc;  // 2*acc exact; single rounding
                    unsigned uu = __float_as_uint(dd);
                    uu = (uu & 0x80000000u) ? ~uu : (uu | 0x80000000u);
                    ek = ((unsigned long long)uu << 32) | (unsigned)col;
                }
            }
        } else {
            // overflow (safety net): exact scan of all columns for this row
            for (int col = lane; col < K_CODES; col += 64) {
                const float* er = embT + (size_t)col * D_DIM;
                float acc = 0.f;
#pragma unroll 8
                for (int d = 0; d < D_DIM; ++d) acc = fmaf(xr[d], er[d], acc);
                float t1 = xn + enorm[col];
                float dd = t1 - 2.0f * acc;
                unsigned uu = __float_as_uint(dd);
                uu = (uu & 0x80000000u) ? ~uu : (uu | 0x80000000u);
                unsigned long long key = ((unsigned long long)uu << 32) | (unsigned)col;
                ek = key < ek ? key : ek;
            }
        }
#pragma unroll
        for (int off = 32; off > 0; off >>= 1) {
            unsigned long long o = __shfl_xor(ek, off, 64);
            ek = o < ek ? o : ek;
        }
        if (lane == 0) idxsh[w] = (int)(unsigned)(ek & 0xFFFFFFFFull);
    }
    __syncthreads();
    // ---- phase 2: verbatim verified k_gather (embIsT = 1) ----
    int row = blockIdx.x * 2 + (tid >> 7);
    int d = (tid & 127) * 4;
    int idx = idxsh[tid >> 7];
    float4 q = *(const float4*)&embT[(size_t)idx * D_DIM + d];
    float4 xv = *(const float4*)&x[(size_t)row * D_DIM + d];
    float d0 = q.x - xv.x, d1 = q.y - xv.y, d2 = q.z - xv.z, d3 = q.w - xv.w;
    float4 o;
    o.x = xv.x + d0; o.y = xv.y + d1; o.z = xv.z + d2; o.w = xv.w + d3;
    *(float4*)&out[(size_t)row * D_DIM + d] = o;
    float s = (d0 * d0 + d1 * d1) + (d2 * d2 + d3 * d3);
#pragma unroll
    for (int off = 32; off > 0; off >>= 1) s += __shfl_xor(s, off, 64);
    __shared__ float wsum[4];
    int wvv = tid >> 6;
    if (lane == 0) wsum[wvv] = s;
    __syncthreads();
    if (tid == 0) partial[blockIdx.x] = (wsum[0] + wsum[1]) + (wsum[2] + wsum[3]);
}

// ---------------------------------------------------------------------------
// Fallback exact fp32 GEMM+argmin (known-good), used when ws is too small.
// ---------------------------------------------------------------------------
__global__ __launch_bounds__(256, 3) void k_argmin(const float* __restrict__ x,
                                                   const float* __restrict__ emb,
                                                   const float* __restrict__ xnorm,
                                                   const float* __restrict__ enorm,
                                                   unsigned long long* __restrict__ keys) {
    __shared__ float As[16 * 128];
    __shared__ float Bs[2][16 * 128];
    const int tid = threadIdx.x;
    const int tx = tid & 15;
    const int ty = tid >> 4;
    const int rowBase = blockIdx.x * 128;
    const int colBase = blockIdx.y * 128;
    const int lane = tid & 63;
    const int wv = tid >> 6;

    float acc[8][8];
#pragma unroll
    for (int j = 0; j < 8; ++j)
#pragma unroll
        for (int i = 0; i < 8; ++i) acc[j][i] = 0.f;

    const int lr = tid >> 2;
    const int ld4 = (tid & 3) * 4;
    const float* gA0 = x + (size_t)(rowBase + lr) * D_DIM + ld4;
    const float* gA1 = gA0 + (size_t)64 * D_DIM;

    const int bd0 = 2 * wv;
    const float* gBbase = emb + (size_t)(bd0 + (lane >> 5)) * K_CODES + colBase + (lane & 31) * 4;

    async_cp16(gBbase, &Bs[0][bd0 * 128]);
    async_cp16(gBbase + (size_t)8 * K_CODES, &Bs[0][(8 + bd0) * 128]);
    float4 pa0 = *(const float4*)gA0;
    float4 pa1 = *(const float4*)gA1;

    const int sg = lr >> 2;
    const int sc = lr & 3;

    for (int c = 0; c < 32; ++c) {
        __syncthreads();
        {
            const float a0v[4] = {pa0.x, pa0.y, pa0.z, pa0.w};
            const float a1v[4] = {pa1.x, pa1.y, pa1.z, pa1.w};
#pragma unroll
            for (int i = 0; i < 4; ++i) {
                int d = ld4 + i;
                int idx = d * 128 + ((sg ^ d) << 2) + sc;
                As[idx] = a0v[i];
                As[idx + 64] = a1v[i];
            }
        }
        __syncthreads();
        if (c + 1 < 32) {
            const int dn = (c + 1) * 16;
            float* bdst = &Bs[(c + 1) & 1][0];
            async_cp16(gBbase + (size_t)dn * K_CODES, bdst + bd0 * 128);
            async_cp16(gBbase + (size_t)(dn + 8) * K_CODES, bdst + (8 + bd0) * 128);
            pa0 = *(const float4*)(gA0 + dn);
            pa1 = *(const float4*)(gA1 + dn);
        }
        const float* B = &Bs[c & 1][0];
#pragma unroll
        for (int d = 0; d < 16; ++d) {
            const float4 a0 = *(const float4*)&As[d * 128 + ((ty ^ d) << 2)];
            const float4 a1 = *(const float4*)&As[d * 128 + ((ty ^ d) << 2) + 64];
            const float4 b0 = *(const float4*)&B[d * 128 + (tx << 2)];
            const float4 b1 = *(const float4*)&B[d * 128 + (tx << 2) + 64];
            const float av[8] = {a0.x, a0.y, a0.z, a0.w, a1.x, a1.y, a1.z, a1.w};
            const float bv[8] = {b0.x, b0.y, b0.z, b0.w, b1.x, b1.y, b1.z, b1.w};
#pragma unroll
            for (int j = 0; j < 8; ++j)
#pragma unroll
                for (int i = 0; i < 8; ++i)
                    acc[j][i] = fmaf(av[j], bv[i], acc[j][i]);
        }
    }

    float en[8];
    *(float4*)&en[0] = *(const float4*)&enorm[colBase + 4 * tx];
    *(float4*)&en[4] = *(const float4*)&enorm[colBase + 64 + 4 * tx];
#pragma unroll
    for (int j = 0; j < 8; ++j) {
        int row = rowBase + ((j < 4) ? (4 * ty + j) : (64 + 4 * ty + (j - 4)));
        float A = xnorm[row];
        unsigned long long best = ~0ull;
#pragma unroll
        for (int i = 0; i < 8; ++i) {
            int col = colBase + ((i < 4) ? (4 * tx + i) : (64 + 4 * tx + (i - 4)));
            float t1 = A + en[i];
            float dd = t1 - 2.0f * acc[j][i];
            unsigned u = __float_as_uint(dd);
            u = (u & 0x80000000u) ? ~u : (u | 0x80000000u);
            unsigned long long key = ((unsigned long long)u << 32) | (unsigned)col;
            best = key < best ? key : best;
        }
#pragma unroll
        for (int off = 8; off > 0; off >>= 1) {
            unsigned long long other = __shfl_xor(best, off, 16);
            best = other < best ? other : best;
        }
        if (tx == 0) atomicMin(&keys[row], best);
    }
}

// fallback gather (reads keys), unchanged
__global__ __launch_bounds__(256) void k_gather(const float* __restrict__ x,
                                                const float* __restrict__ embSrc,
                                                int embIsT,
                                                const unsigned long long* __restrict__ keys,
                                                float* __restrict__ out,
                                                float* __restrict__ partial) {
#pragma clang fp contract(off)
    int tid = threadIdx.x;
    int row = blockIdx.x * 2 + (tid >> 7);
    int d = (tid & 127) * 4;
    int idx = (int)(keys[row] & 0xFFFFFFFFull);
    float4 q;
    if (embIsT) {
        q = *(const float4*)&embSrc[(size_t)idx * D_DIM + d];
    } else {
        q.x = embSrc[(size_t)(d + 0) * K_CODES + idx];
        q.y = embSrc[(size_t)(d + 1) * K_CODES + idx];
        q.z = embSrc[(size_t)(d + 2) * K_CODES + idx];
        q.w = embSrc[(size_t)(d + 3) * K_CODES + idx];
    }
    float4 xv = *(const float4*)&x[(size_t)row * D_DIM + d];
    float d0 = q.x - xv.x, d1 = q.y - xv.y, d2 = q.z - xv.z, d3 = q.w - xv.w;
    float4 o;
    o.x = xv.x + d0; o.y = xv.y + d1; o.z = xv.z + d2; o.w = xv.w + d3;
    *(float4*)&out[(size_t)row * D_DIM + d] = o;
    float s = (d0 * d0 + d1 * d1) + (d2 * d2 + d3 * d3);
#pragma unroll
    for (int off = 32; off > 0; off >>= 1) s += __shfl_xor(s, off, 64);
    __shared__ float wsum[4];
    int lane = tid & 63, wvv = tid >> 6;
    if (lane == 0) wsum[wvv] = s;
    __syncthreads();
    if (tid == 0) partial[blockIdx.x] = (wsum[0] + wsum[1]) + (wsum[2] + wsum[3]);
}

__global__ __launch_bounds__(256) void k_reduce(const float* __restrict__ partial,
                                                float* __restrict__ out) {
    float s = 0.f;
    for (int i = threadIdx.x; i < 16384; i += 256) s += partial[i];
#pragma unroll
    for (int off = 32; off > 0; off >>= 1) s += __shfl_xor(s, off, 64);
    __shared__ float wsum[4];
    int lane = threadIdx.x & 63, wv = threadIdx.x >> 6;
    if (lane == 0) wsum[wv] = s;
    __syncthreads();
    if (threadIdx.x == 0) {
        float t = (wsum[0] + wsum[1]) + (wsum[2] + wsum[3]);
        float m = t / 16777216.f;               // mean((q-x)^2), N*D = 2^24
        out[(size_t)N_ROWS * D_DIM] = 0.25f * m + m;  // beta*m + m
    }
}

extern "C" void kernel_launch(void* const* d_in, const int* in_sizes, int n_in,
                              void* d_out, int out_size, void* d_ws, size_t ws_size,
                              hipStream_t stream) {
    const float* x = (const float*)d_in[0];
    const float* emb = (const float*)d_in[1];
    float* out = (float*)d_out;
    char* ws = (char*)d_ws;

    unsigned long long* keys = (unsigned long long*)(ws + WS_KEYS);
    float* xnorm = (float*)(ws + WS_XNORM);
    float* enorm = (float*)(ws + WS_ENORM);
    float* partial = (float*)(ws + WS_PART);
    float* embT = (float*)(ws + WS_EMBT);

    if (ws_size >= WS_NEED_FAST) {
        unsigned short* ehiT = (unsigned short*)(ws + WS_EHIT);
        unsigned short* xhi = (unsigned short*)(ws + WS_XHI);
        unsigned int* cnt = (unsigned int*)(ws + WS_CNT);
        unsigned long long* cand = (unsigned long long*)(ws + WS_CAND);

        hipLaunchKernelGGL(k_prep_x, dim3(8192), dim3(256), 0, stream, x, xhi, cnt, xnorm);
        hipLaunchKernelGGL(k_prep_e, dim3(576), dim3(256), 0, stream, emb, embT, ehiT, enorm);
        // grid: x = col-blocks (32), y = row-blocks (256) -> A-panel temporal locality
        hipLaunchKernelGGL(k_approx, dim3(K_CODES / 128, N_ROWS / 128), dim3(256), 0, stream,
                           xhi, ehiT, xnorm, enorm, cnt, cand);
        hipLaunchKernelGGL(k_egather, dim3(N_ROWS / 2), dim3(256), 0, stream,
                           x, embT, xnorm, enorm, cnt, cand, out, partial);
        hipLaunchKernelGGL(k_reduce, dim3(1), dim3(256), 0, stream, partial, out);
    } else {
        size_t need = WS_EMBT + (size_t)K_CODES * D_DIM * sizeof(float);
        int useT = (ws_size >= need) ? 1 : 0;

        hipLaunchKernelGGL(k_init, dim3(128), dim3(256), 0, stream, keys, (unsigned int*)nullptr);
        if (useT)
            hipLaunchKernelGGL(k_transpose, dim3(K_CODES / 64, D_DIM / 64), dim3(256), 0, stream,
                               emb, embT);
        hipLaunchKernelGGL(k_xnorm, dim3(N_ROWS / 16), dim3(256), 0, stream, x, xnorm);
        hipLaunchKernelGGL(k_enorm, dim3(K_CODES / 256), dim3(256), 0, stream, emb, enorm);
        hipLaunchKernelGGL(k_argmin, dim3(N_ROWS / 128, K_CODES / 128), dim3(256), 0, stream,
                           x, emb, xnorm, enorm, keys);
        hipLaunchKernelGGL(k_gather, dim3(N_ROWS / 2), dim3(256), 0, stream,
                           x, useT ? embT : emb, useT, keys, out, partial);
        hipLaunchKernelGGL(k_reduce, dim3(1), dim3(256), 0, stream, partial, out);
    }
}

// Round 10
// 694.197 us; speedup vs baseline: 1.1329x; 1.0919x over previous
//
#include <hip/hip_runtime.h>
#include <stdint.h>

#define N_ROWS 32768
#define D_DIM  512
#define K_CODES 4096

// ---- workspace layout (bytes) ----
#define WS_KEYS   0          // u64[32768]            -> 262144   (fallback only)
#define WS_XNORM  262144     // f32[32768]            -> 393216
#define WS_ENORM  393216     // f32[4096]             -> 409600
#define WS_PART   409600     // f32[16384]            -> 475136
#define WS_EMBT   475136     // f32[4096*512] = 8 MiB -> 8863744
// fast-path extras (hi-split only)
#define WS_EHIT   8863744    // u16[4096*512]  = 4 MiB  -> 13058048
#define WS_XHI    13058048   // u16[32768*512] = 32 MiB -> 46612480
#define WS_CNT    46612480   // u32[32768]              -> 46743552
#define WS_CAND   46743552   // u64[32768*64]  = 16 MiB -> 63520768
#define WS_NEED_FAST 63520768ull

// 1-product approx: sim ~ x0*e0 (bf16-truncated hi parts). err_max ~1.2e-2
// (dropped cross terms + fp32 accum-order delta). EPS >= 2*err -> 0.08.
// Verified: absmax == 0.0 at this EPS (rounds 5,6,7,8,9).
#define EPS_CAND 0.08f

typedef __attribute__((address_space(3))) unsigned int lds_uint;
typedef __attribute__((address_space(1))) const unsigned int glob_uint;
__device__ __forceinline__ void async_cp16(const void* g, void* l) {
    // 16B per lane, LDS dest = wave-uniform base + lane*16
    __builtin_amdgcn_global_load_lds((glob_uint*)g, (lds_uint*)l, 16, 0, 0);
}

typedef __attribute__((ext_vector_type(8))) short short8;
typedef __attribute__((ext_vector_type(4))) float f32x4;

__global__ __launch_bounds__(256) void k_init(unsigned long long* keys, unsigned int* cnt) {
    int t = blockIdx.x * 256 + threadIdx.x;
    if (t < N_ROWS) {
        keys[t] = ~0ull;
        if (cnt) cnt[t] = 0u;
    }
}

// ---------------------------------------------------------------------------
// k_prep_x (8192 blocks): split to bf16-hi + cnt init + xnorm of the block's
// own 4 rows (wave 0, verbatim lane pattern -> bitwise-identical xnorm).
// [verified round 8/9]
// ---------------------------------------------------------------------------
__global__ __launch_bounds__(256) void k_prep_x(const float* __restrict__ x,
                                                unsigned short* __restrict__ xhi,
                                                unsigned int* __restrict__ cnt,
                                                float* __restrict__ xnorm) {
#pragma clang fp contract(off)
    const int bid = blockIdx.x;
    const int tid = threadIdx.x;
    if (bid < 128) cnt[bid * 256 + tid] = 0u;
    size_t t = (size_t)bid * 256 + tid;  // 8 floats per thread
    const float4 v0 = *(const float4*)(x + t * 8);
    const float4 v1 = *(const float4*)(x + t * 8 + 4);
    float vs[8] = {v0.x, v0.y, v0.z, v0.w, v1.x, v1.y, v1.z, v1.w};
    unsigned h[8];
#pragma unroll
    for (int i = 0; i < 8; ++i) h[i] = __float_as_uint(vs[i]) >> 16;
    uint4 ph = {h[0] | (h[1] << 16), h[2] | (h[3] << 16),
                h[4] | (h[5] << 16), h[6] | (h[7] << 16)};
    *(uint4*)(xhi + t * 8) = ph;

    // xnorm for rows 4*bid .. 4*bid+3 (wave 0 only; verbatim lane pattern)
    if (tid < 64) {
        int lane = tid;
        int l = lane & 15;
        int rowInWave = lane >> 4;
        int row = bid * 4 + rowInWave;
        const float* xr = x + (size_t)row * D_DIM;
        float B[4];
#pragma unroll
        for (int b = 0; b < 4; ++b) {
            const float* a = xr + b * 128;
            float r[8];
#pragma unroll
            for (int j = 0; j < 8; ++j) {
                float v = a[j * 16 + l];
                r[j] = v * v;
            }
            float V = ((r[0] + r[1]) + (r[2] + r[3])) + ((r[4] + r[5]) + (r[6] + r[7]));
            float T1 = V + __shfl_xor(V, 8);
            float T2 = T1 + __shfl_xor(T1, 4);
            float U  = T2 + __shfl_xor(T2, 2);
            B[b] = U + __shfl_xor(U, 1);
        }
        float total = (B[0] + B[1]) + (B[2] + B[3]);
        if (l == 0) xnorm[row] = total;
    }
}

// ---------------------------------------------------------------------------
// k_prep_e: fused {emb -> embT f32 + ehiT bf16-hi transpose} (blocks 0..511)
// and {enorm, strictly d-ascending serial per col} (blocks 512..575).
// [verified rounds 6-9]
// ---------------------------------------------------------------------------
__global__ __launch_bounds__(256) void k_prep_e(const float* __restrict__ emb,
                                                float* __restrict__ embT,
                                                unsigned short* __restrict__ ehiT,
                                                float* __restrict__ enorm) {
#pragma clang fp contract(off)
    __shared__ float tile[64][65];
    const int bid = blockIdx.x;
    const int tid = threadIdx.x;
    if (bid < 512) {
        int k0 = (bid & 63) * 64;
        int d0 = (bid >> 6) * 64;
        int kk = tid & 63;
        int dth = tid >> 6;
#pragma unroll
        for (int r = 0; r < 16; ++r) {
            int d = dth + r * 4;
            tile[d][kk] = emb[(size_t)(d0 + d) * K_CODES + k0 + kk];
        }
        __syncthreads();
        int dOff = tid & 63;
        int kBase = tid >> 6;
#pragma unroll
        for (int r = 0; r < 16; ++r) {
            int k = kBase + r * 4;
            float v = tile[dOff][k];
            size_t o = (size_t)(k0 + k) * D_DIM + d0 + dOff;
            embT[o] = v;
            ehiT[o] = (unsigned short)(__float_as_uint(v) >> 16);
        }
    } else {
        if (tid < 64) {
            int k = (bid - 512) * 64 + tid;
            float v = emb[k];
            float acc = v * v;
#pragma unroll 8
            for (int d = 1; d < D_DIM; ++d) {
                float u = emb[(size_t)d * K_CODES + k];
                acc = acc + u * u;
            }
            enorm[k] = acc;
        }
    }
}

// fallback-path helpers (unchanged, known-good) -------------------------------
__global__ __launch_bounds__(256) void k_transpose(const float* __restrict__ emb,
                                                   float* __restrict__ embT) {
    __shared__ float tile[64][65];
    int k0 = blockIdx.x * 64;
    int d0 = blockIdx.y * 64;
    int tid = threadIdx.x;
    int kk = tid & 63;
    int dd = tid >> 6;
#pragma unroll
    for (int r = 0; r < 16; ++r) {
        int d = dd + r * 4;
        tile[d][kk] = emb[(size_t)(d0 + d) * K_CODES + k0 + kk];
    }
    __syncthreads();
    int dOff = tid & 63;
    int kBase = tid >> 6;
#pragma unroll
    for (int r = 0; r < 16; ++r) {
        int k = kBase + r * 4;
        embT[(size_t)(k0 + k) * D_DIM + d0 + dOff] = tile[dOff][k];
    }
}

__global__ __launch_bounds__(256) void k_xnorm(const float* __restrict__ x,
                                               float* __restrict__ xnorm) {
#pragma clang fp contract(off)
    int lane = threadIdx.x & 63;
    int l = lane & 15;
    int rowInWave = lane >> 4;
    int wave = blockIdx.x * 4 + (threadIdx.x >> 6);
    int row = wave * 4 + rowInWave;
    const float* xr = x + (size_t)row * D_DIM;
    float B[4];
#pragma unroll
    for (int b = 0; b < 4; ++b) {
        const float* a = xr + b * 128;
        float r[8];
#pragma unroll
        for (int j = 0; j < 8; ++j) {
            float v = a[j * 16 + l];
            r[j] = v * v;
        }
        float V = ((r[0] + r[1]) + (r[2] + r[3])) + ((r[4] + r[5]) + (r[6] + r[7]));
        float T1 = V + __shfl_xor(V, 8);
        float T2 = T1 + __shfl_xor(T1, 4);
        float U  = T2 + __shfl_xor(T2, 2);
        B[b] = U + __shfl_xor(U, 1);
    }
    float total = (B[0] + B[1]) + (B[2] + B[3]);
    if (l == 0) xnorm[row] = total;
}

__global__ __launch_bounds__(256) void k_enorm(const float* __restrict__ emb,
                                               float* __restrict__ enorm) {
#pragma clang fp contract(off)
    int k = blockIdx.x * 256 + threadIdx.x;
    float v = emb[k];
    float acc = v * v;
    for (int d = 1; d < D_DIM; ++d) {
        float u = emb[(size_t)d * K_CODES + k];
        acc = acc + u * u;
    }
    enorm[k] = acc;
}

// ---------------------------------------------------------------------------
// Fast path: 1-product bf16-hi MFMA approximate distances + eps-candidates.
// ROUND-5 CONFIG RESTORED VERBATIM — the best-measured variant (314 us):
// BK=32 double-buffered, counted-vmcnt pipeline (vmcnt(4) keeps next chunk's
// 4 cp16 in flight across the barrier), 2 barriers/chunk, 32 KB LDS,
// __launch_bounds__(256,4) -> 4 blocks/CU (VGPR 64, no spill).
// Structural variants all measured WORSE: A-direct-reg 403 (r7, uncoalesced),
// (256,5) 413 (r8, VGPR 48 spill, WRITE 259MB), triple-buf 3-block 390 (r9,
// occupancy loss > barrier gain). setprio: null (r6). Do not change.
// ---------------------------------------------------------------------------
__global__ __launch_bounds__(256, 4) void k_approx(
    const unsigned short* __restrict__ xhi, const unsigned short* __restrict__ ehiT,
    const float* __restrict__ xnorm, const float* __restrict__ enorm,
    unsigned int* __restrict__ cnt, unsigned long long* __restrict__ cand) {
    __shared__ short As[2][128 * 32];  // [buf][row m][k granule-swizzled]
    __shared__ short Bs[2][128 * 32];  // [buf][col n][k]
    const int tid = threadIdx.x;
    const int lane = tid & 63;
    const int wv = tid >> 6;
    const int rowBase = blockIdx.y * 128;
    const int colBase = blockIdx.x * 128;
    const int mBase = (wv >> 1) * 64;
    const int nBase = (wv & 1) * 64;

    f32x4 acc[4][4];
#pragma unroll
    for (int i = 0; i < 4; ++i)
#pragma unroll
        for (int j = 0; j < 4; ++j) acc[i][j] = (f32x4){0.f, 0.f, 0.f, 0.f};

    // staging: wave wv covers rows [wv*32, wv*32+32) of A and B.
    // lane -> (row = rr + lane>>2, slot = lane&3); slot holds global granule
    // g = slot ^ ((row>>1)&3)  (XOR involution; read side applies the same).
    auto STAGE = [&](int buf, int c) {
#pragma unroll
        for (int i = 0; i < 2; ++i) {
            const int rr = wv * 32 + i * 16;       // 16 rows per cp16
            const int row = rr + (lane >> 2);
            const int g = (lane & 3) ^ ((row >> 1) & 3);
            const size_t kO = (size_t)c * 32 + g * 8;
            async_cp16(xhi + (size_t)(rowBase + row) * 512 + kO, &As[buf][rr * 32]);
            async_cp16(ehiT + (size_t)(colBase + row) * 512 + kO, &Bs[buf][rr * 32]);
        }
    };

    const int gk = lane >> 4;   // k-slice 0..3 (8 shorts each)
    const int lm = lane & 15;

    auto COMPUTE = [&](int buf) {
        short8 a[4], b[4];
#pragma unroll
        for (int mf = 0; mf < 4; ++mf) {
            const int m = mBase + mf * 16 + lm;
            a[mf] = *(const short8*)&As[buf][m * 32 + ((gk ^ ((m >> 1) & 3)) << 3)];
        }
#pragma unroll
        for (int nf = 0; nf < 4; ++nf) {
            const int n = nBase + nf * 16 + lm;
            b[nf] = *(const short8*)&Bs[buf][n * 32 + ((gk ^ ((n >> 1) & 3)) << 3)];
        }
#pragma unroll
        for (int mf = 0; mf < 4; ++mf)
#pragma unroll
            for (int nf = 0; nf < 4; ++nf)
                acc[mf][nf] = __builtin_amdgcn_mfma_f32_16x16x32_bf16(a[mf], b[nf], acc[mf][nf], 0, 0, 0);
    };

    STAGE(0, 0);
    STAGE(1, 1);
#pragma unroll 1
    for (int c = 0; c < 15; ++c) {
        // STAGE(c)'s 4 loads done; STAGE(c+1)'s 4 stay in flight across barrier
        asm volatile("s_waitcnt vmcnt(4)" ::: "memory");
        __builtin_amdgcn_sched_barrier(0);
        __builtin_amdgcn_s_barrier();
        COMPUTE(c & 1);
        __builtin_amdgcn_sched_barrier(0);
        __builtin_amdgcn_s_barrier();   // all waves done reading buf[c&1]
        if (c < 14) STAGE(c & 1, c + 2);
    }
    // last chunk (c=15): only STAGE(15)'s 4 loads outstanding
    asm volatile("s_waitcnt vmcnt(0)" ::: "memory");
    __builtin_amdgcn_sched_barrier(0);
    __builtin_amdgcn_s_barrier();
    COMPUTE(1);

    // ---- epilogue: dd = (xn+en) - 2*sim; per-row block min; candidate append ----
    const int lr4 = (lane >> 4) * 4;  // C/D: row = (lane>>4)*4 + reg
    const int lc = lane & 15;         //      col = lane & 15
    float en[4], xn[4][4];
#pragma unroll
    for (int nf = 0; nf < 4; ++nf) en[nf] = enorm[colBase + nBase + nf * 16 + lc];
#pragma unroll
    for (int mf = 0; mf < 4; ++mf)
#pragma unroll
        for (int reg = 0; reg < 4; ++reg)
            xn[mf][reg] = xnorm[rowBase + mBase + mf * 16 + lr4 + reg];

#pragma unroll
    for (int mf = 0; mf < 4; ++mf)
#pragma unroll
        for (int nf = 0; nf < 4; ++nf) {
            f32x4 a = acc[mf][nf];
#pragma unroll
            for (int reg = 0; reg < 4; ++reg)
                a[reg] = (xn[mf][reg] + en[nf]) - 2.0f * a[reg];
            acc[mf][nf] = a;
        }

    __syncthreads();                 // done reading As/Bs; reuse As for row mins
    float* rm = (float*)&As[0][0];   // [2 col-halves][128 rows]
#pragma unroll
    for (int mf = 0; mf < 4; ++mf)
#pragma unroll
        for (int reg = 0; reg < 4; ++reg) {
            float v = fminf(fminf(acc[mf][0][reg], acc[mf][1][reg]),
                            fminf(acc[mf][2][reg], acc[mf][3][reg]));
            v = fminf(v, __shfl_xor(v, 1, 16));
            v = fminf(v, __shfl_xor(v, 2, 16));
            v = fminf(v, __shfl_xor(v, 4, 16));
            v = fminf(v, __shfl_xor(v, 8, 16));
            if (lc == 0) rm[(wv & 1) * 128 + mBase + mf * 16 + lr4 + reg] = v;
        }
    __syncthreads();

#pragma unroll
    for (int mf = 0; mf < 4; ++mf)
#pragma unroll
        for (int reg = 0; reg < 4; ++reg) {
            const int rLoc = mBase + mf * 16 + lr4 + reg;
            const float thr = fminf(rm[rLoc], rm[128 + rLoc]) + EPS_CAND;
            const int rowG = rowBase + rLoc;
#pragma unroll
            for (int nf = 0; nf < 4; ++nf) {
                float dd = acc[mf][nf][reg];
                if (dd <= thr) {
                    unsigned u = __float_as_uint(dd);
                    u = (u & 0x80000000u) ? ~u : (u | 0x80000000u);
                    const unsigned colG = (unsigned)(colBase + nBase + nf * 16 + lc);
                    unsigned long long key = ((unsigned long long)u << 32) | colG;
                    unsigned idx = atomicAdd(&cnt[rowG], 1u);
                    if (idx < 64u) cand[(size_t)rowG * 64 + idx] = key;
                }
            }
        }
}

// ---------------------------------------------------------------------------
// k_egather: fused exact-rescan + gather + loss (verified rounds 6-9).
// ---------------------------------------------------------------------------
__global__ __launch_bounds__(256) void k_egather(
    const float* __restrict__ x, const float* __restrict__ embT,
    const float* __restrict__ xnorm, const float* __restrict__ enorm,
    const unsigned int* __restrict__ cnt, const unsigned long long* __restrict__ cand,
    float* __restrict__ out, float* __restrict__ partial) {
#pragma clang fp contract(off)
    __shared__ int idxsh[2];
    const int tid = threadIdx.x;
    const int w = tid >> 6;
    const int lane = tid & 63;
    if (w < 2) {
        const int row = blockIdx.x * 2 + w;
        const unsigned n = cnt[row];
        const float xn = xnorm[row];
        const float* xr = x + (size_t)row * D_DIM;
        unsigned long long ek = ~0ull;
        if (n <= 64u) {
            unsigned long long kk = ~0ull;
            if (lane < (int)n) kk = cand[(size_t)row * 64 + lane];
            unsigned long long mn = kk;
#pragma unroll
            for (int off = 32; off > 0; off >>= 1) {
                unsigned long long o = __shfl_xor(mn, off, 64);
                mn = o < mn ? o : mn;
            }
            unsigned mu = (unsigned)(mn >> 32);
            float mnf = __uint_as_float((mu & 0x80000000u) ? (mu & 0x7FFFFFFFu) : ~mu);
            if (lane < (int)n) {
                unsigned u = (unsigned)(kk >> 32);
                float ddA = __uint_as_float((u & 0x80000000u) ? (u & 0x7FFFFFFFu) : ~u);
                int col = (int)(unsigned)(kk & 0xFFFFFFFFull);
                if (ddA <= mnf + EPS_CAND) {
                    const float* er = embT + (size_t)col * D_DIM;
                    float acc = 0.f;
#pragma unroll 8
                    for (int d = 0; d < D_DIM; ++d) acc = fmaf(xr[d], er[d], acc);
                    float t1 = xn + enorm[col];
                    float dd = t1 - 2.0f * acc;  // 2*acc exact; single rounding
                    unsigned uu = __float_as_uint(dd);
                    uu = (uu & 0x80000000u) ? ~uu : (uu | 0x80000000u);
                    ek = ((unsigned long long)uu << 32) | (unsigned)col;
                }
            }
        } else {
            // overflow (safety net): exact scan of all columns for this row
            for (int col = lane; col < K_CODES; col += 64) {
                const float* er = embT + (size_t)col * D_DIM;
                float acc = 0.f;
#pragma unroll 8
                for (int d = 0; d < D_DIM; ++d) acc = fmaf(xr[d], er[d], acc);
                float t1 = xn + enorm[col];
                float dd = t1 - 2.0f * acc;
                unsigned uu = __float_as_uint(dd);
                uu = (uu & 0x80000000u) ? ~uu : (uu | 0x80000000u);
                unsigned long long key = ((unsigned long long)uu << 32) | (unsigned)col;
                ek = key < ek ? key : ek;
            }
        }
#pragma unroll
        for (int off = 32; off > 0; off >>= 1) {
            unsigned long long o = __shfl_xor(ek, off, 64);
            ek = o < ek ? o : ek;
        }
        if (lane == 0) idxsh[w] = (int)(unsigned)(ek & 0xFFFFFFFFull);
    }
    __syncthreads();
    // ---- phase 2: verbatim verified k_gather (embIsT = 1) ----
    int row = blockIdx.x * 2 + (tid >> 7);
    int d = (tid & 127) * 4;
    int idx = idxsh[tid >> 7];
    float4 q = *(const float4*)&embT[(size_t)idx * D_DIM + d];
    float4 xv = *(const float4*)&x[(size_t)row * D_DIM + d];
    float d0 = q.x - xv.x, d1 = q.y - xv.y, d2 = q.z - xv.z, d3 = q.w - xv.w;
    float4 o;
    o.x = xv.x + d0; o.y = xv.y + d1; o.z = xv.z + d2; o.w = xv.w + d3;
    *(float4*)&out[(size_t)row * D_DIM + d] = o;
    float s = (d0 * d0 + d1 * d1) + (d2 * d2 + d3 * d3);
#pragma unroll
    for (int off = 32; off > 0; off >>= 1) s += __shfl_xor(s, off, 64);
    __shared__ float wsum[4];
    int wvv = tid >> 6;
    if (lane == 0) wsum[wvv] = s;
    __syncthreads();
    if (tid == 0) partial[blockIdx.x] = (wsum[0] + wsum[1]) + (wsum[2] + wsum[3]);
}

// ---------------------------------------------------------------------------
// Fallback exact fp32 GEMM+argmin (known-good), used when ws is too small.
// ---------------------------------------------------------------------------
__global__ __launch_bounds__(256, 3) void k_argmin(const float* __restrict__ x,
                                                   const float* __restrict__ emb,
                                                   const float* __restrict__ xnorm,
                                                   const float* __restrict__ enorm,
                                                   unsigned long long* __restrict__ keys) {
    __shared__ float As[16 * 128];
    __shared__ float Bs[2][16 * 128];
    const int tid = threadIdx.x;
    const int tx = tid & 15;
    const int ty = tid >> 4;
    const int rowBase = blockIdx.x * 128;
    const int colBase = blockIdx.y * 128;
    const int lane = tid & 63;
    const int wv = tid >> 6;

    float acc[8][8];
#pragma unroll
    for (int j = 0; j < 8; ++j)
#pragma unroll
        for (int i = 0; i < 8; ++i) acc[j][i] = 0.f;

    const int lr = tid >> 2;
    const int ld4 = (tid & 3) * 4;
    const float* gA0 = x + (size_t)(rowBase + lr) * D_DIM + ld4;
    const float* gA1 = gA0 + (size_t)64 * D_DIM;

    const int bd0 = 2 * wv;
    const float* gBbase = emb + (size_t)(bd0 + (lane >> 5)) * K_CODES + colBase + (lane & 31) * 4;

    async_cp16(gBbase, &Bs[0][bd0 * 128]);
    async_cp16(gBbase + (size_t)8 * K_CODES, &Bs[0][(8 + bd0) * 128]);
    float4 pa0 = *(const float4*)gA0;
    float4 pa1 = *(const float4*)gA1;

    const int sg = lr >> 2;
    const int sc = lr & 3;

    for (int c = 0; c < 32; ++c) {
        __syncthreads();
        {
            const float a0v[4] = {pa0.x, pa0.y, pa0.z, pa0.w};
            const float a1v[4] = {pa1.x, pa1.y, pa1.z, pa1.w};
#pragma unroll
            for (int i = 0; i < 4; ++i) {
                int d = ld4 + i;
                int idx = d * 128 + ((sg ^ d) << 2) + sc;
                As[idx] = a0v[i];
                As[idx + 64] = a1v[i];
            }
        }
        __syncthreads();
        if (c + 1 < 32) {
            const int dn = (c + 1) * 16;
            float* bdst = &Bs[(c + 1) & 1][0];
            async_cp16(gBbase + (size_t)dn * K_CODES, bdst + bd0 * 128);
            async_cp16(gBbase + (size_t)(dn + 8) * K_CODES, bdst + (8 + bd0) * 128);
            pa0 = *(const float4*)(gA0 + dn);
            pa1 = *(const float4*)(gA1 + dn);
        }
        const float* B = &Bs[c & 1][0];
#pragma unroll
        for (int d = 0; d < 16; ++d) {
            const float4 a0 = *(const float4*)&As[d * 128 + ((ty ^ d) << 2)];
            const float4 a1 = *(const float4*)&As[d * 128 + ((ty ^ d) << 2) + 64];
            const float4 b0 = *(const float4*)&B[d * 128 + (tx << 2)];
            const float4 b1 = *(const float4*)&B[d * 128 + (tx << 2) + 64];
            const float av[8] = {a0.x, a0.y, a0.z, a0.w, a1.x, a1.y, a1.z, a1.w};
            const float bv[8] = {b0.x, b0.y, b0.z, b0.w, b1.x, b1.y, b1.z, b1.w};
#pragma unroll
            for (int j = 0; j < 8; ++j)
#pragma unroll
                for (int i = 0; i < 8; ++i)
                    acc[j][i] = fmaf(av[j], bv[i], acc[j][i]);
        }
    }

    float en[8];
    *(float4*)&en[0] = *(const float4*)&enorm[colBase + 4 * tx];
    *(float4*)&en[4] = *(const float4*)&enorm[colBase + 64 + 4 * tx];
#pragma unroll
    for (int j = 0; j < 8; ++j) {
        int row = rowBase + ((j < 4) ? (4 * ty + j) : (64 + 4 * ty + (j - 4)));
        float A = xnorm[row];
        unsigned long long best = ~0ull;
#pragma unroll
        for (int i = 0; i < 8; ++i) {
            int col = colBase + ((i < 4) ? (4 * tx + i) : (64 + 4 * tx + (i - 4)));
            float t1 = A + en[i];
            float dd = t1 - 2.0f * acc[j][i];
            unsigned u = __float_as_uint(dd);
            u = (u & 0x80000000u) ? ~u : (u | 0x80000000u);
            unsigned long long key = ((unsigned long long)u << 32) | (unsigned)col;
            best = key < best ? key : best;
        }
#pragma unroll
        for (int off = 8; off > 0; off >>= 1) {
            unsigned long long other = __shfl_xor(best, off, 16);
            best = other < best ? other : best;
        }
        if (tx == 0) atomicMin(&keys[row], best);
    }
}

// fallback gather (reads keys), unchanged
__global__ __launch_bounds__(256) void k_gather(const float* __restrict__ x,
                                                const float* __restrict__ embSrc,
                                                int embIsT,
                                                const unsigned long long* __restrict__ keys,
                                                float* __restrict__ out,
                                                float* __restrict__ partial) {
#pragma clang fp contract(off)
    int tid = threadIdx.x;
    int row = blockIdx.x * 2 + (tid >> 7);
    int d = (tid & 127) * 4;
    int idx = (int)(keys[row] & 0xFFFFFFFFull);
    float4 q;
    if (embIsT) {
        q = *(const float4*)&embSrc[(size_t)idx * D_DIM + d];
    } else {
        q.x = embSrc[(size_t)(d + 0) * K_CODES + idx];
        q.y = embSrc[(size_t)(d + 1) * K_CODES + idx];
        q.z = embSrc[(size_t)(d + 2) * K_CODES + idx];
        q.w = embSrc[(size_t)(d + 3) * K_CODES + idx];
    }
    float4 xv = *(const float4*)&x[(size_t)row * D_DIM + d];
    float d0 = q.x - xv.x, d1 = q.y - xv.y, d2 = q.z - xv.z, d3 = q.w - xv.w;
    float4 o;
    o.x = xv.x + d0; o.y = xv.y + d1; o.z = xv.z + d2; o.w = xv.w + d3;
    *(float4*)&out[(size_t)row * D_DIM + d] = o;
    float s = (d0 * d0 + d1 * d1) + (d2 * d2 + d3 * d3);
#pragma unroll
    for (int off = 32; off > 0; off >>= 1) s += __shfl_xor(s, off, 64);
    __shared__ float wsum[4];
    int lane = tid & 63, wvv = tid >> 6;
    if (lane == 0) wsum[wvv] = s;
    __syncthreads();
    if (tid == 0) partial[blockIdx.x] = (wsum[0] + wsum[1]) + (wsum[2] + wsum[3]);
}

__global__ __launch_bounds__(256) void k_reduce(const float* __restrict__ partial,
                                                float* __restrict__ out) {
    float s = 0.f;
    for (int i = threadIdx.x; i < 16384; i += 256) s += partial[i];
#pragma unroll
    for (int off = 32; off > 0; off >>= 1) s += __shfl_xor(s, off, 64);
    __shared__ float wsum[4];
    int lane = threadIdx.x & 63, wv = threadIdx.x >> 6;
    if (lane == 0) wsum[wv] = s;
    __syncthreads();
    if (threadIdx.x == 0) {
        float t = (wsum[0] + wsum[1]) + (wsum[2] + wsum[3]);
        float m = t / 16777216.f;               // mean((q-x)^2), N*D = 2^24
        out[(size_t)N_ROWS * D_DIM] = 0.25f * m + m;  // beta*m + m
    }
}

extern "C" void kernel_launch(void* const* d_in, const int* in_sizes, int n_in,
                              void* d_out, int out_size, void* d_ws, size_t ws_size,
                              hipStream_t stream) {
    const float* x = (const float*)d_in[0];
    const float* emb = (const float*)d_in[1];
    float* out = (float*)d_out;
    char* ws = (char*)d_ws;

    unsigned long long* keys = (unsigned long long*)(ws + WS_KEYS);
    float* xnorm = (float*)(ws + WS_XNORM);
    float* enorm = (float*)(ws + WS_ENORM);
    float* partial = (float*)(ws + WS_PART);
    float* embT = (float*)(ws + WS_EMBT);

    if (ws_size >= WS_NEED_FAST) {
        unsigned short* ehiT = (unsigned short*)(ws + WS_EHIT);
        unsigned short* xhi = (unsigned short*)(ws + WS_XHI);
        unsigned int* cnt = (unsigned int*)(ws + WS_CNT);
        unsigned long long* cand = (unsigned long long*)(ws + WS_CAND);

        hipLaunchKernelGGL(k_prep_x, dim3(8192), dim3(256), 0, stream, x, xhi, cnt, xnorm);
        hipLaunchKernelGGL(k_prep_e, dim3(576), dim3(256), 0, stream, emb, embT, ehiT, enorm);
        // grid: x = col-blocks (32), y = row-blocks (256) -> A-panel temporal locality
        hipLaunchKernelGGL(k_approx, dim3(K_CODES / 128, N_ROWS / 128), dim3(256), 0, stream,
                           xhi, ehiT, xnorm, enorm, cnt, cand);
        hipLaunchKernelGGL(k_egather, dim3(N_ROWS / 2), dim3(256), 0, stream,
                           x, embT, xnorm, enorm, cnt, cand, out, partial);
        hipLaunchKernelGGL(k_reduce, dim3(1), dim3(256), 0, stream, partial, out);
    } else {
        size_t need = WS_EMBT + (size_t)K_CODES * D_DIM * sizeof(float);
        int useT = (ws_size >= need) ? 1 : 0;

        hipLaunchKernelGGL(k_init, dim3(128), dim3(256), 0, stream, keys, (unsigned int*)nullptr);
        if (useT)
            hipLaunchKernelGGL(k_transpose, dim3(K_CODES / 64, D_DIM / 64), dim3(256), 0, stream,
                               emb, embT);
        hipLaunchKernelGGL(k_xnorm, dim3(N_ROWS / 16), dim3(256), 0, stream, x, xnorm);
        hipLaunchKernelGGL(k_enorm, dim3(K_CODES / 256), dim3(256), 0, stream, emb, enorm);
        hipLaunchKernelGGL(k_argmin, dim3(N_ROWS / 128, K_CODES / 128), dim3(256), 0, stream,
                           x, emb, xnorm, enorm, keys);
        hipLaunchKernelGGL(k_gather, dim3(N_ROWS / 2), dim3(256), 0, stream,
                           x, useT ? embT : emb, useT, keys, out, partial);
        hipLaunchKernelGGL(k_reduce, dim3(1), dim3(256), 0, stream, partial, out);
    }
}